// Round 13
// baseline (456.285 us; speedup 1.0000x reference)
//
#include <hip/hip_runtime.h>

// TopK-and-scatter: out[r,c] = x[r,c] if x[r,c] is among the top-64 of row r
// (ties at threshold broken by LOWEST column index, matching lax.top_k), else 0.
// R13: SINGLE memory pass + static-threshold candidate compaction.
// Stream the row once: write zeros everywhere, atomic-append elements with
// (int)bits > 0x40000000 (x > 2.0f, positives only) to an LDS candidate list.
// If >=64 candidates exist, the top-64 are all in the list (any 64 elements
// > 2.0 outrank everything <= 2.0). Select then runs on ~750 candidates, not
// 32768: 1024-bin mini-histogram -> suffix scan -> exact packed-key rank of
// the crossing bin -> scatter <=64 dwords over the already-written zeros.
// Zero+scatter same-block ordering proven exact in R9 (syncthreads drains
// vmcnt before scatter issues). Exact streaming bitwise-search fallback for
// C<64 / C>CAP / crossing-bin>EQCAP — correct for ANY input (never taken for
// the benchmark's N(0,1) data: per-row count(x>2) in [646, 844] w/ 6.7-sigma
// margin to CAP=1024).

typedef unsigned int u32;
typedef unsigned long long u64;
typedef u32 u32x4 __attribute__((ext_vector_type(4)));

#define TPB    256
#define COLS   32768
#define VPT    32          // u32x4 vectors per thread
#define KSEL   64u
#define CAP    1024u
#define EQCAP  256u
#define THR    0x40000000  // bits of 2.0f

__device__ __forceinline__ u32 toKey(u32 b) {
    return b ^ ((u32)((int)b >> 31) | 0x80000000u);
}

__device__ __forceinline__ u32 blockSum(u32 v, volatile u32* wt, int lane, int wid)
{
    #pragma unroll
    for (int off = 32; off >= 1; off >>= 1) v += __shfl_down(v, off);
    if (lane == 0) wt[wid] = v;
    __syncthreads();
    u32 t = 0;
    #pragma unroll
    for (int w = 0; w < 4; ++w) t += wt[w];
    __syncthreads();
    return t;
}

__global__ __launch_bounds__(TPB) void topk_scatter_kernel(
    const float* __restrict__ x, float* __restrict__ out)
{
    __shared__ u32 hist[1024];            // 4 KB
    __shared__ u64 candPk[CAP];           // 8 KB
    __shared__ u64 eqPk[EQCAP];           // 2 KB
    __shared__ u32 wtot[4];
    __shared__ int sBin;
    __shared__ u32 sAbove, sEqCnt, candN, eqN;

    const int tid  = threadIdx.x;
    const int lane = tid & 63;
    const int wid  = tid >> 6;

    const long long row = blockIdx.x;
    const u32x4* __restrict__ xrow = (const u32x4*)(x + row * (long long)COLS);
    u32x4* __restrict__ orow       = (u32x4*)(out + row * (long long)COLS);
    u32*   __restrict__ orowU      = (u32*)(out + row * (long long)COLS);

    ((u32x4*)hist)[tid] = (u32x4)(0u);
    if (tid == 0) { candN = 0u; eqN = 0u; sBin = -1; }
    __syncthreads();                                   // A

    // ---- single pass: load, zero-store, append candidates (> 2.0f) ----
    #pragma unroll 1
    for (int g = 0; g < 4; ++g) {
        u32x4 v[8];
        #pragma unroll
        for (int j = 0; j < 8; ++j) v[j] = xrow[(g * 8 + j) * TPB + tid];
        #pragma unroll
        for (int j = 0; j < 8; ++j) orow[(g * 8 + j) * TPB + tid] = (u32x4)(0u);
        #pragma unroll
        for (int j = 0; j < 8; ++j) {
            #pragma unroll
            for (int l = 0; l < 4; ++l) {
                const u32 k = v[j][l];
                if ((int)k > (int)THR) {
                    const u32 p = atomicAdd(&candN, 1u);
                    const u32 col = (u32)(((g * 8 + j) * TPB + tid) * 4 + l);
                    if (p < CAP) candPk[p] = ((u64)k << 32) | (u32)(~col);
                }
            }
        }
    }
    __syncthreads();                       // B: zero-stores drained, candN final

    const u32 C = candN;
    bool done = false;

    if (C >= KSEL && C <= CAP) {
        // ---- mini histogram over candidates: bins (bits-THR)>>15, clamped ----
        for (u32 i = tid; i < C; i += TPB) {
            const u32 k = (u32)(candPk[i] >> 32);
            u32 idx = (k - (u32)THR) >> 15;
            if (idx > 1023u) idx = 1023u;
            atomicAdd(&hist[idx], 1u);
        }
        __syncthreads();                   // C: mini-hist ready
        // ---- suffix scan: thread owns bins [4*tid, 4*tid+4) ----
        {
            const u32x4 h = ((const u32x4*)hist)[tid];
            const u32 ls3 = h[3];
            const u32 ls2 = h[2] + ls3;
            const u32 ls1 = h[1] + ls2;
            const u32 ls0 = h[0] + ls1;
            u32 v = ls0;
            #pragma unroll
            for (int off = 1; off < 64; off <<= 1) {
                const u32 t = __shfl_down(v, off);
                if (lane + off < 64) v += t;
            }
            if (lane == 0) wtot[wid] = v;
            __syncthreads();               // D: wtot ready
            u32 tail = 0u;
            #pragma unroll
            for (int w = 0; w < 4; ++w) if (w > wid) tail += wtot[w];
            const u32 thrTail = tail + (v - ls0);
            const u32 S0 = ls0 + thrTail, S1 = ls1 + thrTail, S2 = ls2 + thrTail,
                      S3 = ls3 + thrTail, S4 = thrTail;
            if (S0 >= KSEL && S1 < KSEL) { sBin = 4*tid+0; sAbove = S1; sEqCnt = h[0]; }
            if (S1 >= KSEL && S2 < KSEL) { sBin = 4*tid+1; sAbove = S2; sEqCnt = h[1]; }
            if (S2 >= KSEL && S3 < KSEL) { sBin = 4*tid+2; sAbove = S3; sEqCnt = h[2]; }
            if (S3 >= KSEL && S4 < KSEL) { sBin = 4*tid+3; sAbove = S4; sEqCnt = h[3]; }
            __syncthreads();               // E: crossing known (exists: C>=KSEL)
        }
        const u32 b1     = (u32)sBin;
        const u32 need   = KSEL - sAbove;  // 1..binCnt
        const u32 binCnt = sEqCnt;

        if (binCnt <= EQCAP) {
            // ---- collect crossing-bin members ----
            for (u32 i = tid; i < C; i += TPB) {
                const u32 k = (u32)(candPk[i] >> 32);
                u32 idx = (k - (u32)THR) >> 15;
                if (idx > 1023u) idx = 1023u;
                if (idx == b1) { const u32 p = atomicAdd(&eqN, 1u); eqPk[p] = candPk[i]; }
            }
            __syncthreads();               // F: eq list ready
            const u32 E2 = eqN;            // == binCnt
            // ---- scatter: bins>b1 direct; bin==b1 by exact packed rank ----
            for (u32 i = tid; i < C; i += TPB) {
                const u64 pk = candPk[i];
                const u32 k  = (u32)(pk >> 32);
                u32 idx = (k - (u32)THR) >> 15;
                if (idx > 1023u) idx = 1023u;
                bool sel = (idx > b1);
                if (idx == b1) {
                    u32 r = 0;
                    for (u32 q = 0; q < E2; ++q) r += (eqPk[q] > pk) ? 1u : 0u;
                    sel = (r < need);
                }
                if (sel) orowU[~(u32)pk] = k;
            }
            done = true;
        }
    }

    if (!done) {
        // ---- exact slow path: streaming bitwise searches + scatter ----
        u32 pfx = 0u;
        for (int bit = 31; bit >= 0; --bit) {
            const u32 trial = pfx | (1u << bit);
            u32 loc = 0u;
            #pragma unroll 1
            for (int m = 0; m < VPT; ++m) {
                const u32x4 v = xrow[m * TPB + tid];
                #pragma unroll
                for (int l = 0; l < 4; ++l) loc += (toKey(v[l]) >= trial) ? 1u : 0u;
            }
            if (blockSum(loc, wtot, lane, wid) >= KSEL) pfx = trial;
        }
        const u32 T = pfx;                             // 64th largest key
        u32 loc = 0u;
        #pragma unroll 1
        for (int m = 0; m < VPT; ++m) {
            const u32x4 v = xrow[m * TPB + tid];
            #pragma unroll
            for (int l = 0; l < 4; ++l) loc += (toKey(v[l]) > T) ? 1u : 0u;
        }
        const u32 needEq = KSEL - blockSum(loc, wtot, lane, wid);
        u32 cv = 0u;
        for (int bit = 14; bit >= 0; --bit) {
            const u32 trial = cv | (1u << bit);
            u32 l2 = 0u;
            #pragma unroll 1
            for (int m = 0; m < VPT; ++m) {
                const u32x4 v = xrow[m * TPB + tid];
                #pragma unroll
                for (int l = 0; l < 4; ++l) {
                    const u32 col = (u32)((m * TPB + tid) * 4 + l);
                    l2 += (toKey(v[l]) == T && col < trial) ? 1u : 0u;
                }
            }
            if (blockSum(l2, wtot, lane, wid) < needEq) cv = trial;
        }
        const u32 colT = cv;
        #pragma unroll 1
        for (int m = 0; m < VPT; ++m) {
            const u32x4 v = xrow[m * TPB + tid];
            #pragma unroll
            for (int l = 0; l < 4; ++l) {
                const u32 k = toKey(v[l]);
                const u32 col = (u32)((m * TPB + tid) * 4 + l);
                if ((k > T) || (k == T && col <= colT)) orowU[col] = v[l];
            }
        }
    }
}

extern "C" void kernel_launch(void* const* d_in, const int* in_sizes, int n_in,
                              void* d_out, int out_size, void* d_ws, size_t ws_size,
                              hipStream_t stream)
{
    (void)n_in; (void)out_size; (void)d_ws; (void)ws_size;
    const float* x = (const float*)d_in[0];
    float* out = (float*)d_out;
    const int rows = in_sizes[0] / COLS;
    topk_scatter_kernel<<<dim3(rows), dim3(TPB), 0, stream>>>(x, out);
}